// Round 1
// baseline (245.170 us; speedup 1.0000x reference)
//
#include <hip/hip_runtime.h>
#include <hip/hip_bf16.h>

#define CS 384
#define CH 32
#define CZ 128
#define LL 384
#define NL 1536   // N*L
#define EPS 1e-5f

// ---------------- Kernel 1: LayerNorm + A = sn@W1+b1, B = sn@W2+b2 ------------
__global__ __launch_bounds__(128) void k_ln_ab(
    const float* __restrict__ s, const float* __restrict__ g, const float* __restrict__ be,
    const float* __restrict__ W1, const float* __restrict__ b1,
    const float* __restrict__ W2, const float* __restrict__ b2,
    float* __restrict__ A, float* __restrict__ B)
{
    const int row = blockIdx.x;
    const int t   = threadIdx.x;
    const int wid = t >> 6, lane = t & 63;
    const float* srow = s + (size_t)row * CS;

    __shared__ float sn[CS];
    __shared__ float red[2];

    float x0 = srow[t], x1 = srow[t + 128], x2 = srow[t + 256];

    // mean
    float p = x0 + x1 + x2;
    #pragma unroll
    for (int o = 32; o > 0; o >>= 1) p += __shfl_down(p, o);
    if (lane == 0) red[wid] = p;
    __syncthreads();
    const float mu = (red[0] + red[1]) * (1.0f / CS);
    __syncthreads();

    // variance
    float d0 = x0 - mu, d1 = x1 - mu, d2 = x2 - mu;
    float q = d0 * d0 + d1 * d1 + d2 * d2;
    #pragma unroll
    for (int o = 32; o > 0; o >>= 1) q += __shfl_down(q, o);
    if (lane == 0) red[wid] = q;
    __syncthreads();
    const float var = (red[0] + red[1]) * (1.0f / CS);
    const float rstd = rsqrtf(var + EPS);

    sn[t]       = d0 * rstd * g[t]       + be[t];
    sn[t + 128] = d1 * rstd * g[t + 128] + be[t + 128];
    sn[t + 256] = d2 * rstd * g[t + 256] + be[t + 256];
    __syncthreads();

    if (t < 64) {
        const int h = t & 31;
        const float* W  = (t < 32) ? W1 : W2;
        const float* bb = (t < 32) ? b1 : b2;
        float acc = bb[h];
        #pragma unroll 4
        for (int c = 0; c < CS; ++c)
            acc += sn[c] * W[c * CH + h];
        float* dst = (t < 32) ? A : B;
        dst[(size_t)row * CH + h] = acc;
    }
}

// ---------------- Kernel 2: M[r,d,z] = sum_c A[r,c] * Wo[c,d,z] --------------
// GEMM: [NL,32] x [32, 4096] -> [NL, 4096]; 8 rows per block.
__global__ __launch_bounds__(256) void k_m(
    const float* __restrict__ A, const float* __restrict__ Wo, float* __restrict__ M)
{
    const int t  = threadIdx.x;
    const int r0 = blockIdx.x * 8;
    __shared__ float Al[8][CH];
    Al[t >> 5][t & 31] = A[(size_t)(r0 + (t >> 5)) * CH + (t & 31)];
    __syncthreads();

    for (int cb = 0; cb < CH * CZ; cb += 256) {
        const int col = cb + t;
        float acc[8];
        #pragma unroll
        for (int r = 0; r < 8; ++r) acc[r] = 0.0f;
        #pragma unroll
        for (int c = 0; c < CH; ++c) {
            const float wv = Wo[(size_t)c * (CH * CZ) + col];
            #pragma unroll
            for (int r = 0; r < 8; ++r) acc[r] += Al[r][c] * wv;
        }
        #pragma unroll
        for (int r = 0; r < 8; ++r)
            M[(size_t)(r0 + r) * (CH * CZ) + col] = acc[r];
    }
}

// ---------------- Kernel 3: out[r,j,z] = sum_d B[n,j,d]*M[r,d,z] + bo[z] -----
// One block per r = n*L+i; thread z holds M[:,z] in 32 VGPRs; loops over j.
__global__ __launch_bounds__(128) void k_out(
    const float* __restrict__ B, const float* __restrict__ M,
    const float* __restrict__ bo, float* __restrict__ out)
{
    const int r = blockIdx.x;
    const int z = threadIdx.x;
    const int n = r / LL;

    float m[CH];
    const float* Mr = M + (size_t)r * (CH * CZ);
    #pragma unroll
    for (int d = 0; d < CH; ++d) m[d] = Mr[d * CZ + z];

    const float bz = bo[z];
    const float* Bn = B + (size_t)n * LL * CH;
    float* outr = out + (size_t)r * LL * CZ;

    for (int j = 0; j < LL; ++j) {
        const float* br = Bn + j * CH;
        float acc = bz;
        #pragma unroll
        for (int d = 0; d < CH; ++d) acc += br[d] * m[d];
        outr[(size_t)j * CZ + z] = acc;
    }
}

extern "C" void kernel_launch(void* const* d_in, const int* in_sizes, int n_in,
                              void* d_out, int out_size, void* d_ws, size_t ws_size,
                              hipStream_t stream) {
    const float* s  = (const float*)d_in[0];
    const float* g  = (const float*)d_in[1];
    const float* be = (const float*)d_in[2];
    const float* W1 = (const float*)d_in[3];
    const float* b1 = (const float*)d_in[4];
    const float* W2 = (const float*)d_in[5];
    const float* b2 = (const float*)d_in[6];
    const float* Wo = (const float*)d_in[7];
    const float* bo = (const float*)d_in[8];
    float* out = (float*)d_out;

    const size_t nA = (size_t)NL * CH;
    const size_t nM = (size_t)NL * CH * CZ;
    if (ws_size < (nA * 2 + nM) * sizeof(float)) return;  // fail visibly, no UB

    float* A  = (float*)d_ws;
    float* Bm = A + nA;
    float* M  = Bm + nA;

    k_ln_ab<<<NL, 128, 0, stream>>>(s, g, be, W1, b1, W2, b2, A, Bm);
    k_m   <<<NL / 8, 256, 0, stream>>>(A, Wo, M);
    k_out <<<NL, 128, 0, stream>>>(Bm, M, bo, out);
}

// Round 2
// 153.037 us; speedup vs baseline: 1.6020x; 1.6020x over previous
//
#include <hip/hip_runtime.h>
#include <hip/hip_bf16.h>

#define CS 384
#define CH 32
#define CZ 128
#define LL 384
#define NL 1536   // N*L
#define EPS 1e-5f

// ---------------- Kernel 1: LayerNorm + A = sn@W1+b1, B = sn@W2+b2 ------------
__global__ __launch_bounds__(128) void k_ln_ab(
    const float* __restrict__ s, const float* __restrict__ g, const float* __restrict__ be,
    const float* __restrict__ W1, const float* __restrict__ b1,
    const float* __restrict__ W2, const float* __restrict__ b2,
    float* __restrict__ A, float* __restrict__ B)
{
    const int row = blockIdx.x;
    const int t   = threadIdx.x;
    const int wid = t >> 6, lane = t & 63;
    const float* srow = s + (size_t)row * CS;

    __shared__ float sn[CS];
    __shared__ float red[2];
    __shared__ float part[128];

    float x0 = srow[t], x1 = srow[t + 128], x2 = srow[t + 256];

    // mean
    float p = x0 + x1 + x2;
    #pragma unroll
    for (int o = 32; o > 0; o >>= 1) p += __shfl_down(p, o);
    if (lane == 0) red[wid] = p;
    __syncthreads();
    const float mu = (red[0] + red[1]) * (1.0f / CS);
    __syncthreads();

    // variance
    float d0 = x0 - mu, d1 = x1 - mu, d2 = x2 - mu;
    float q = d0 * d0 + d1 * d1 + d2 * d2;
    #pragma unroll
    for (int o = 32; o > 0; o >>= 1) q += __shfl_down(q, o);
    if (lane == 0) red[wid] = q;
    __syncthreads();
    const float var = (red[0] + red[1]) * (1.0f / CS);
    const float rstd = rsqrtf(var + EPS);

    sn[t]       = d0 * rstd * g[t]       + be[t];
    sn[t + 128] = d1 * rstd * g[t + 128] + be[t + 128];
    sn[t + 256] = d2 * rstd * g[t + 256] + be[t + 256];
    __syncthreads();

    // matvec: all 128 threads. t -> (half = t>>6, mat = (t>>5)&1, h = t&31)
    {
        const int h    = t & 31;
        const int mat  = (t >> 5) & 1;
        const int half = t >> 6;
        const float* W = mat ? W2 : W1;
        float acc = 0.0f;
        const int c0 = half * (CS / 2);
        #pragma unroll 8
        for (int c = c0; c < c0 + CS / 2; ++c)
            acc += sn[c] * W[c * CH + h];
        part[t] = acc;
    }
    __syncthreads();
    if (t < 64) {
        const int h   = t & 31;
        const int mat = t >> 5;
        const float v = part[t] + part[t + 64] + (mat ? b2[h] : b1[h]);
        (mat ? B : A)[(size_t)row * CH + h] = v;
    }
}

// ---------------- Kernel 2: M[r,d,z] = sum_c A[r,c] * Wo[c,d,z] --------------
// GEMM: [NL,32] x [32,4096] -> [NL,4096]; 4 rows/block, float4 cols.
__global__ __launch_bounds__(256) void k_m(
    const float* __restrict__ A, const float* __restrict__ Wo, float* __restrict__ M)
{
    const int t  = threadIdx.x;
    const int r0 = blockIdx.x * 4;
    __shared__ float Al[4][CH];
    if (t < 128) Al[t >> 5][t & 31] = A[(size_t)(r0 + (t >> 5)) * CH + (t & 31)];
    __syncthreads();

    const float4* Wo4 = (const float4*)Wo;      // 1024 float4 per c-row
    float4*       M4  = (float4*)M;

    for (int g4 = t; g4 < 1024; g4 += 256) {
        float4 acc[4];
        #pragma unroll
        for (int r = 0; r < 4; ++r) acc[r] = make_float4(0.f, 0.f, 0.f, 0.f);
        #pragma unroll 8
        for (int c = 0; c < CH; ++c) {
            const float4 wv = Wo4[(size_t)c * 1024 + g4];
            #pragma unroll
            for (int r = 0; r < 4; ++r) {
                const float a = Al[r][c];
                acc[r].x += a * wv.x; acc[r].y += a * wv.y;
                acc[r].z += a * wv.z; acc[r].w += a * wv.w;
            }
        }
        #pragma unroll
        for (int r = 0; r < 4; ++r)
            M4[(size_t)(r0 + r) * 1024 + g4] = acc[r];
    }
}

// ---------------- Kernel 3: out[r,j,z] = sum_d B[n,j,d]*M[r,d,z] + bo[z] -----
// One block per r; thread z holds M[:,z] in 32 VGPRs; 2 j's per iter, float4 b.
__global__ __launch_bounds__(128) void k_out(
    const float* __restrict__ B, const float* __restrict__ M,
    const float* __restrict__ bo, float* __restrict__ out)
{
    const int r = blockIdx.x;
    const int z = threadIdx.x;
    const int n = r / LL;

    float m[CH];
    const float* Mr = M + (size_t)r * (CH * CZ);
    #pragma unroll
    for (int d = 0; d < CH; ++d) m[d] = Mr[d * CZ + z];

    const float bz = bo[z];
    const float4* Bn = (const float4*)(B + (size_t)n * LL * CH);  // 8 float4/row
    float* outr = out + (size_t)r * LL * CZ;

    for (int j = 0; j < LL; j += 2) {
        float4 b0[8], b1[8];
        #pragma unroll
        for (int q = 0; q < 8; ++q) b0[q] = Bn[(size_t)j * 8 + q];
        #pragma unroll
        for (int q = 0; q < 8; ++q) b1[q] = Bn[(size_t)(j + 1) * 8 + q];

        float acc0 = bz, acc1 = bz;
        #pragma unroll
        for (int q = 0; q < 8; ++q) {
            acc0 += b0[q].x * m[4*q+0]; acc0 += b0[q].y * m[4*q+1];
            acc0 += b0[q].z * m[4*q+2]; acc0 += b0[q].w * m[4*q+3];
        }
        #pragma unroll
        for (int q = 0; q < 8; ++q) {
            acc1 += b1[q].x * m[4*q+0]; acc1 += b1[q].y * m[4*q+1];
            acc1 += b1[q].z * m[4*q+2]; acc1 += b1[q].w * m[4*q+3];
        }
        outr[(size_t)j * CZ + z]       = acc0;
        outr[(size_t)(j + 1) * CZ + z] = acc1;
    }
}

extern "C" void kernel_launch(void* const* d_in, const int* in_sizes, int n_in,
                              void* d_out, int out_size, void* d_ws, size_t ws_size,
                              hipStream_t stream) {
    const float* s  = (const float*)d_in[0];
    const float* g  = (const float*)d_in[1];
    const float* be = (const float*)d_in[2];
    const float* W1 = (const float*)d_in[3];
    const float* b1 = (const float*)d_in[4];
    const float* W2 = (const float*)d_in[5];
    const float* b2 = (const float*)d_in[6];
    const float* Wo = (const float*)d_in[7];
    const float* bo = (const float*)d_in[8];
    float* out = (float*)d_out;

    const size_t nA = (size_t)NL * CH;
    const size_t nM = (size_t)NL * CH * CZ;
    if (ws_size < (nA * 2 + nM) * sizeof(float)) return;  // fail visibly, no UB

    float* A  = (float*)d_ws;
    float* Bm = A + nA;
    float* M  = Bm + nA;

    k_ln_ab<<<NL, 128, 0, stream>>>(s, g, be, W1, b1, W2, b2, A, Bm);
    k_m   <<<NL / 4, 256, 0, stream>>>(A, Wo, M);
    k_out <<<NL, 128, 0, stream>>>(Bm, M, bo, out);
}